// Round 12
// baseline (670.912 us; speedup 1.0000x reference)
//
#include <hip/hip_runtime.h>
#include <math.h>

#define NN 10000
#define NE 160000
#define NT 50000

typedef unsigned short u16;
typedef unsigned int u32;
typedef __attribute__((ext_vector_type(8))) short bf16x8;
typedef __attribute__((ext_vector_type(4))) float f32x4;

__device__ __forceinline__ float bf2f(u16 u) { return __uint_as_float(((u32)u) << 16); }
__device__ __forceinline__ u16 f2bf(float f) {
    u32 x = __float_as_uint(f);
    return (u16)((x + 0x7fffu + ((x >> 16) & 1u)) >> 16);
}
// HW packed f32->bf16 (RNE)
__device__ __forceinline__ u32 cvtpk(float a, float b) {
    u32 r;
    asm("v_cvt_pk_bf16_f32 %0, %1, %2" : "=v"(r) : "v"(a), "v"(b));
    return r;
}
__device__ __forceinline__ float lrelu(float x) { return x > 0.f ? x : 0.2f * x; }

#define MFMA16(a, b, c) __builtin_amdgcn_mfma_f32_16x16x32_bf16((a), (b), (c), 0, 0, 0)

// ---------------------------------------------------------------------------
// Prep: pack pointnet W1/W2/W3 into MFMA B-fragment order.
// B-frag pack of W == A-frag pack of W^T, so W1f/W2f/W3f serve as A-operands
// for the fully swapped pointnet.
// ---------------------------------------------------------------------------
__global__ void k_wfrag(const float* __restrict__ W1, const float* __restrict__ W2,
                        const float* __restrict__ W3,
                        u16* __restrict__ W1f, u16* __restrict__ W2f, u16* __restrict__ W3f) {
    int i = blockIdx.x * 256 + threadIdx.x;
    if (i < 2048) {
        int e = i & 7, l = (i >> 3) & 63, nt = i >> 9;
        int k = (l >> 4) * 8 + e, c = nt * 16 + (l & 15);
        W1f[i] = (k < 16) ? f2bf(W1[k * 64 + c]) : (u16)0;
    }
    if (i < 8192) {
        int e = i & 7, l = (i >> 3) & 63, nt = (i >> 9) & 7, ks = i >> 12;
        int k = ks * 32 + (l >> 4) * 8 + e, c = nt * 16 + (l & 15);
        W2f[i] = f2bf(W2[k * 128 + c]);
    }
    if (i < 32768) {
        int e = i & 7, l = (i >> 3) & 63, nt = (i >> 9) & 15, ks = i >> 13;
        int k = ks * 32 + (l >> 4) * 8 + e, c = nt * 16 + (l & 15);
        W3f[i] = f2bf(W3[k * 256 + c]);
    }
}

// ---------------------------------------------------------------------------
// Generic weight pack: fp32 [K x M] -> bf16 frag order [ceil64(K)/32][M/16][64][8]
// ---------------------------------------------------------------------------
__global__ void k_pack(const float* __restrict__ W, u16* __restrict__ Wf, int K, int Mt) {
    int total = (((K + 63) & ~63) >> 5) * Mt * 512;
    for (int i = blockIdx.x * 256 + threadIdx.x; i < total; i += gridDim.x * 256) {
        int e = i & 7, l = (i >> 3) & 63, mt = (i >> 9) % Mt, kk = i / (Mt << 9);
        int k = (kk << 5) + ((l >> 4) << 3) + e;
        int c = (mt << 4) + (l & 15);
        Wf[i] = (k < K) ? f2bf(W[(size_t)k * (Mt << 4) + c]) : (u16)0;
    }
}

// ---------------------------------------------------------------------------
// MFMA point-net v3: ALL THREE layers swapped (D = W^T · act^T). h1 and h2
// live entirely in registers; layer-2 and layer-3 B-frags built via in-wave
// shuffle transposes of the previous layer's packed D-frags. Max-pool over
// points = in-wave shfl_xor over lr + 4KB cross-wave LDS combine. No 32KB
// staging buffer, no big barrier, ~zero bank conflicts.
// ---------------------------------------------------------------------------
__global__ __launch_bounds__(256) void k_pointnet_mfma(
    const float* __restrict__ x,
    const u16* __restrict__ W1f, const float* __restrict__ b1,
    const u16* __restrict__ W2f, const float* __restrict__ b2,
    const u16* __restrict__ W3f, const float* __restrict__ b3,
    u16* __restrict__ featb)
{
    __shared__ float pool[4][256];   // 4 KB cross-wave pool buffer

    const int node = blockIdx.x;
    const int t = threadIdx.x;
    const int w = t >> 6;
    const int l = t & 63;
    const int lr = l & 15;
    const int lg = l >> 4;

    // ---- layer 1 (swapped): h1^T[ch=64][pt], this wave's 32 pts ----------
    u32 pk1[4][2][2];   // [cht][ptt][pair]: lane holds ch = cht*16+4*lg+{2p,2p+1}, pt = ptt*16+lr
    {
        union { u32 q[4]; bf16x8 v; } xb0, xb1;
        xb0.q[0] = xb0.q[1] = xb0.q[2] = xb0.q[3] = 0;
        xb1 = xb0;
        if (lg < 2) {
            const float* px = x + ((size_t)node * 128 + w * 32 + lr) * 16 + lg * 8;
            float4 f0 = *(const float4*)px;
            float4 f1 = *(const float4*)(px + 4);
            xb0.q[0] = cvtpk(f0.x, f0.y); xb0.q[1] = cvtpk(f0.z, f0.w);
            xb0.q[2] = cvtpk(f1.x, f1.y); xb0.q[3] = cvtpk(f1.z, f1.w);
            float4 g0 = *(const float4*)(px + 256);
            float4 g1 = *(const float4*)(px + 260);
            xb1.q[0] = cvtpk(g0.x, g0.y); xb1.q[1] = cvtpk(g0.z, g0.w);
            xb1.q[2] = cvtpk(g1.x, g1.y); xb1.q[3] = cvtpk(g1.z, g1.w);
        }
        #pragma unroll
        for (int cht = 0; cht < 4; ++cht) {
            f32x4 ci = *(const f32x4*)(b1 + cht * 16 + 4 * lg);
            bf16x8 wf = *(const bf16x8*)(W1f + (cht * 64 + l) * 8);
            f32x4 a0 = MFMA16(wf, xb0.v, ci);
            f32x4 a1 = MFMA16(wf, xb1.v, ci);
            pk1[cht][0][0] = cvtpk(fmaxf(a0[0], 0.f), fmaxf(a0[1], 0.f));
            pk1[cht][0][1] = cvtpk(fmaxf(a0[2], 0.f), fmaxf(a0[3], 0.f));
            pk1[cht][1][0] = cvtpk(fmaxf(a1[0], 0.f), fmaxf(a1[1], 0.f));
            pk1[cht][1][1] = cvtpk(fmaxf(a1[2], 0.f), fmaxf(a1[3], 0.f));
        }
    }

    // ---- layer 2 (swapped): h2^T = W2^T @ h1^T, B via shuffle transpose ---
    u32 pk2[8][2][2];   // h2 packed, same layout convention as pk1
    {
        f32x4 acc2[8][2];
        #pragma unroll
        for (int mt = 0; mt < 8; ++mt) {
            f32x4 ci = *(const f32x4*)(b2 + mt * 16 + 4 * lg);
            acc2[mt][0] = ci;
            acc2[mt][1] = ci;
        }
        #pragma unroll
        for (int ks = 0; ks < 2; ++ks) {
            union { u32 q[4]; bf16x8 v; } B2[2];
            #pragma unroll
            for (int ptt = 0; ptt < 2; ++ptt) {
                #pragma unroll
                for (int j = 0; j < 4; ++j) {
                    int s = ((2 * (lg & 1) + (j >> 1)) << 4) + lr;
                    int lo = __shfl((int)pk1[2 * ks][ptt][j & 1], s);
                    int hi = __shfl((int)pk1[2 * ks + 1][ptt][j & 1], s);
                    B2[ptt].q[j] = (u32)((lg >> 1) ? hi : lo);
                }
            }
            #pragma unroll
            for (int mt = 0; mt < 8; ++mt) {
                bf16x8 af = *(const bf16x8*)(W2f + ((ks * 8 + mt) * 64 + l) * 8);
                acc2[mt][0] = MFMA16(af, B2[0].v, acc2[mt][0]);
                acc2[mt][1] = MFMA16(af, B2[1].v, acc2[mt][1]);
            }
        }
        #pragma unroll
        for (int mt = 0; mt < 8; ++mt) {
            #pragma unroll
            for (int ptt = 0; ptt < 2; ++ptt) {
                pk2[mt][ptt][0] = cvtpk(fmaxf(acc2[mt][ptt][0], 0.f), fmaxf(acc2[mt][ptt][1], 0.f));
                pk2[mt][ptt][1] = cvtpk(fmaxf(acc2[mt][ptt][2], 0.f), fmaxf(acc2[mt][ptt][3], 0.f));
            }
        }
    }

    // ---- layer-3 B-frags from pk2 (same shuffle-transpose pattern) --------
    union { u32 q[4]; bf16x8 v; } B3[4][2];   // [ks=ch/32][ptt]
    #pragma unroll
    for (int ks = 0; ks < 4; ++ks) {
        #pragma unroll
        for (int ptt = 0; ptt < 2; ++ptt) {
            #pragma unroll
            for (int j = 0; j < 4; ++j) {
                int s = ((2 * (lg & 1) + (j >> 1)) << 4) + lr;
                int lo = __shfl((int)pk2[2 * ks][ptt][j & 1], s);
                int hi = __shfl((int)pk2[2 * ks + 1][ptt][j & 1], s);
                B3[ks][ptt].q[j] = (u32)((lg >> 1) ? hi : lo);
            }
        }
    }

    // ---- layer 3 (swapped): out^T = W3^T @ h2^T, pool over pts ------------
    #pragma unroll
    for (int half = 0; half < 2; ++half) {   // outch tiles 0-7 / 8-15
        f32x4 acc3[8][2];
        #pragma unroll
        for (int oc = 0; oc < 8; ++oc) {
            f32x4 ci = *(const f32x4*)(b3 + (half * 8 + oc) * 16 + 4 * lg);
            acc3[oc][0] = ci;
            acc3[oc][1] = ci;
        }
        #pragma unroll
        for (int ks = 0; ks < 4; ++ks) {
            #pragma unroll
            for (int oc = 0; oc < 8; ++oc) {
                bf16x8 af = *(const bf16x8*)(W3f + ((ks * 16 + half * 8 + oc) * 64 + l) * 8);
                acc3[oc][0] = MFMA16(af, B3[ks][0].v, acc3[oc][0]);
                acc3[oc][1] = MFMA16(af, B3[ks][1].v, acc3[oc][1]);
            }
        }
        #pragma unroll
        for (int oc = 0; oc < 8; ++oc) {
            f32x4 m;
            #pragma unroll
            for (int r = 0; r < 4; ++r)
                m[r] = fmaxf(fmaxf(acc3[oc][0][r], acc3[oc][1][r]), 0.f);
            #pragma unroll
            for (int o = 1; o < 16; o <<= 1) {
                #pragma unroll
                for (int r = 0; r < 4; ++r)
                    m[r] = fmaxf(m[r], __shfl_xor(m[r], o));
            }
            if (lr == 0)
                *(f32x4*)&pool[w][(half * 8 + oc) * 16 + 4 * lg] = m;
        }
    }
    __syncthreads();
    if (t < 256) {
        float v = fmaxf(fmaxf(pool[0][t], pool[1][t]), fmaxf(pool[2][t], pool[3][t]));
        featb[(size_t)node * 256 + t] = f2bf(v);
    }
}

// ---------------------------------------------------------------------------
// Generic bf16 MFMA GEMM (unchanged).
// ---------------------------------------------------------------------------
template<int CT, int DUAL, int RELU, int OUTM, int NORMA>
__global__ __launch_bounds__(256) void k_mm(
    const u16* __restrict__ A, const u16* __restrict__ A2,
    const u16* __restrict__ Bf, const u16* __restrict__ B2f,
    const float* __restrict__ bias, int K, int Mt,
    void* __restrict__ outp,
    const float* __restrict__ scale_ptr, int scale_idx,
    const float* __restrict__ mu, const float* __restrict__ inv)
{
    __shared__ u16 As[8192];
    __shared__ u16 As2[DUAL ? 8192 : 8];

    const int t = threadIdx.x;
    const int l = t & 63, lr = l & 15, lg = l >> 4;
    const int row0 = blockIdx.y << 7;
    const int ct0 = blockIdx.x * CT;
    const int m0 = (t >> 6) << 5;

    f32x4 acc[2][CT];
    #pragma unroll
    for (int nt = 0; nt < CT; ++nt) {
        float bv = bias ? bias[((ct0 + nt) << 4) + lr] : 0.f;
        f32x4 ci = {bv, bv, bv, bv};
        acc[0][nt] = ci;
        acc[1][nt] = ci;
    }

    const int KS = (K + 63) >> 6;
    for (int kblk = 0; kblk < KS; ++kblk) {
        const int k0 = kblk << 6;
        if (kblk) __syncthreads();
        #pragma unroll
        for (int j = 0; j < 4; ++j) {
            int si = t + (j << 8);
            int row = si >> 3, seg = si & 7;
            int gr = row0 + row;
            int kb = k0 + (seg << 3);
            int soff = ((row << 6) + (seg << 3)) ^ ((row & 7) << 3);
            if (NORMA) {
                u32 q0 = 0, q1 = 0, q2 = 0, q3 = 0;
                if (gr < NN) {
                    const float* Af = (const float*)A;
                    float4 f0 = *(const float4*)(Af + (size_t)gr * K + kb);
                    float4 f1 = *(const float4*)(Af + (size_t)gr * K + kb + 4);
                    q0 = cvtpk((f0.x - mu[kb+0]) * inv[kb+0], (f0.y - mu[kb+1]) * inv[kb+1]);
                    q1 = cvtpk((f0.z - mu[kb+2]) * inv[kb+2], (f0.w - mu[kb+3]) * inv[kb+3]);
                    q2 = cvtpk((f1.x - mu[kb+4]) * inv[kb+4], (f1.y - mu[kb+5]) * inv[kb+5]);
                    q3 = cvtpk((f1.z - mu[kb+6]) * inv[kb+6], (f1.w - mu[kb+7]) * inv[kb+7]);
                }
                u32* dst = (u32*)&As[soff];
                dst[0] = q0; dst[1] = q1; dst[2] = q2; dst[3] = q3;
            } else {
                bf16x8 v = {0,0,0,0,0,0,0,0};
                bf16x8 v2 = {0,0,0,0,0,0,0,0};
                if (gr < NN) {
                    if (kb + 8 <= K) {
                        v = *(const bf16x8*)(A + (size_t)gr * K + kb);
                        if (DUAL) v2 = *(const bf16x8*)(A2 + (size_t)gr * K + kb);
                    } else {
                        #pragma unroll
                        for (int e = 0; e < 8; ++e) if (kb + e < K) {
                            v[e] = (short)A[(size_t)gr * K + kb + e];
                            if (DUAL) v2[e] = (short)A2[(size_t)gr * K + kb + e];
                        }
                    }
                }
                *(bf16x8*)&As[soff] = v;
                if (DUAL) *(bf16x8*)&As2[soff] = v2;
            }
        }
        __syncthreads();
        #pragma unroll
        for (int ks = 0; ks < 2; ++ks) {
            const int kk = (k0 >> 5) + ks;
            bf16x8 bfr[CT];
            #pragma unroll
            for (int nt = 0; nt < CT; ++nt)
                bfr[nt] = *(const bf16x8*)(Bf + (((size_t)kk * Mt + ct0 + nt) << 9) + (l << 3));
            #pragma unroll
            for (int mt = 0; mt < 2; ++mt) {
                int row = m0 + (mt << 4) + lr;
                int soff = ((row << 6) + (ks << 5) + (lg << 3)) ^ ((row & 7) << 3);
                bf16x8 af = *(const bf16x8*)&As[soff];
                #pragma unroll
                for (int nt = 0; nt < CT; ++nt)
                    acc[mt][nt] = MFMA16(af, bfr[nt], acc[mt][nt]);
            }
            if (DUAL) {
                bf16x8 bfr2[CT];
                #pragma unroll
                for (int nt = 0; nt < CT; ++nt)
                    bfr2[nt] = *(const bf16x8*)(B2f + (((size_t)kk * Mt + ct0 + nt) << 9) + (l << 3));
                #pragma unroll
                for (int mt = 0; mt < 2; ++mt) {
                    int row = m0 + (mt << 4) + lr;
                    int soff = ((row << 6) + (ks << 5) + (lg << 3)) ^ ((row & 7) << 3);
                    bf16x8 af2 = *(const bf16x8*)&As2[soff];
                    #pragma unroll
                    for (int nt = 0; nt < CT; ++nt)
                        acc[mt][nt] = MFMA16(af2, bfr2[nt], acc[mt][nt]);
                }
            }
        }
    }

    float scale = 1.f;
    if (OUTM == 1 || OUTM == 2) scale = scale_ptr[scale_idx];
    const int M = Mt << 4;
    #pragma unroll
    for (int mt = 0; mt < 2; ++mt) {
        #pragma unroll
        for (int nt = 0; nt < CT; ++nt) {
            int col = ((ct0 + nt) << 4) + lr;
            #pragma unroll
            for (int r = 0; r < 4; ++r) {
                int grow = row0 + m0 + (mt << 4) + (lg << 2) + r;
                if (grow >= NN) continue;
                float v = acc[mt][nt][r];
                if (RELU) v = fmaxf(v, 0.f);
                size_t o = (size_t)grow * M + col;
                if (OUTM == 0) ((u16*)outp)[o] = f2bf(v);
                else if (OUTM == 1) ((float*)outp)[o] = scale * v;
                else if (OUTM == 2) ((float*)outp)[o] += scale * v;
                else ((float*)outp)[o] = v;
            }
        }
    }
}

// ---------------------------------------------------------------------------
// CSR build
// ---------------------------------------------------------------------------
__global__ void k_init(int* counts, float* s1, float* s2) {
    int i = blockIdx.x * 256 + threadIdx.x;
    if (i < NN) counts[i] = 0;
    if (i < 512) { s1[i] = 0.f; s2[i] = 0.f; }
}

__global__ void k_csr_count(const int* __restrict__ EI, int* counts) {
    int e = blockIdx.x * 256 + threadIdx.x;
    if (e < NE) atomicAdd(&counts[EI[NE + e]], 1);
}

__global__ __launch_bounds__(1024) void k_scan(const int* __restrict__ counts,
                                               int* offs, int* cursor) {
    __shared__ int buf[1024];
    int t = threadIdx.x;
    int carry = 0;
    for (int chunk = 0; chunk < (NN + 1023) / 1024; ++chunk) {
        int i = chunk * 1024 + t;
        int v = (i < NN) ? counts[i] : 0;
        buf[t] = v;
        __syncthreads();
        for (int o = 1; o < 1024; o <<= 1) {
            int xv = (t >= o) ? buf[t - o] : 0;
            __syncthreads();
            buf[t] += xv;
            __syncthreads();
        }
        int excl = buf[t] - v;
        if (i < NN) { offs[i] = carry + excl; cursor[i] = carry + excl; }
        carry += buf[1023];
        __syncthreads();
    }
    if (t == 0) offs[NN] = carry;
}

__global__ void k_csr_scatter(const int* __restrict__ EI, int* cursor, int* csrc) {
    int e = blockIdx.x * 256 + threadIdx.x;
    if (e < NE) {
        int d = EI[NE + e];
        int pos = atomicAdd(&cursor[d], 1);
        csrc[pos] = EI[e];
    }
}

// ---------------------------------------------------------------------------
// Fused aggregations (as round 11).
// ---------------------------------------------------------------------------
template<int WU>
__global__ void k_agg2same(const u32* __restrict__ in, u32* __restrict__ out_mean,
                           u32* __restrict__ out_agg,
                           const int* __restrict__ offs, const int* __restrict__ srcs)
{
    int node = blockIdx.x;
    int c = threadIdx.x;
    int o0 = offs[node], o1 = offs[node + 1];
    float s0 = 0.f, s1 = 0.f;
    for (int j = o0; j < o1; ++j) {
        u32 v = in[(size_t)srcs[j] * WU + c];
        s0 += bf2f((u16)(v & 0xffff));
        s1 += bf2f((u16)(v >> 16));
    }
    int d = o1 - o0;
    float r = 1.f / (float)(d > 0 ? d : 1);
    out_mean[(size_t)node * WU + c] = cvtpk(s0 * r, s1 * r);
    u32 v = in[(size_t)node * WU + c];
    out_agg[(size_t)node * WU + c] = cvtpk(s0 + bf2f((u16)(v & 0xffff)),
                                           s1 + bf2f((u16)(v >> 16)));
}

template<int WU>
__global__ void k_agg2two(const u32* __restrict__ inM, const u32* __restrict__ inS,
                          u32* __restrict__ outM, u32* __restrict__ outS,
                          const int* __restrict__ offs, const int* __restrict__ srcs)
{
    int node = blockIdx.x;
    int c = threadIdx.x;
    int o0 = offs[node], o1 = offs[node + 1];
    float m0 = 0.f, m1 = 0.f, s0 = 0.f, s1 = 0.f;
    for (int j = o0; j < o1; ++j) {
        int sc = srcs[j];
        u32 a = inM[(size_t)sc * WU + c];
        u32 b = inS[(size_t)sc * WU + c];
        m0 += bf2f((u16)(a & 0xffff)); m1 += bf2f((u16)(a >> 16));
        s0 += bf2f((u16)(b & 0xffff)); s1 += bf2f((u16)(b >> 16));
    }
    int d = o1 - o0;
    float r = 1.f / (float)(d > 0 ? d : 1);
    outM[(size_t)node * WU + c] = cvtpk(m0 * r, m1 * r);
    u32 v = inS[(size_t)node * WU + c];
    outS[(size_t)node * WU + c] = cvtpk(s0 + bf2f((u16)(v & 0xffff)),
                                        s1 + bf2f((u16)(v >> 16)));
}

// ---------------------------------------------------------------------------
// GAT (bf16 features)
// ---------------------------------------------------------------------------
__global__ void k_gat1_al(const u16* __restrict__ h, const float* __restrict__ a_s,
                          const float* __restrict__ a_d, float* als, float* ald) {
    int idx = blockIdx.x * 64 + threadIdx.x;
    if (idx >= NN * 8) return;
    int node = idx >> 3, hh = idx & 7;
    float s = 0.f, d = 0.f;
    #pragma unroll
    for (int c = 0; c < 10; ++c) {
        float hv = bf2f(h[node * 80 + hh * 10 + c]);
        s = fmaf(hv, a_s[hh * 10 + c], s);
        d = fmaf(hv, a_d[hh * 10 + c], d);
    }
    als[idx] = s; ald[idx] = d;
}

__global__ __launch_bounds__(128) void k_gat1_attn(
    const u16* __restrict__ h, const float* __restrict__ als,
    const float* __restrict__ ald, const float* __restrict__ bias,
    const int* __restrict__ offs, const int* __restrict__ srcs,
    u16* __restrict__ ha)
{
    int node = blockIdx.x;
    int t = threadIdx.x;
    if (t >= 80) return;
    int hh = t / 10;
    int o0 = offs[node], o1 = offs[node + 1];
    float ad = ald[node * 8 + hh];
    float eself = lrelu(als[node * 8 + hh] + ad);
    float m = eself;
    for (int j = o0; j < o1; ++j)
        m = fmaxf(m, lrelu(als[srcs[j] * 8 + hh] + ad));
    float den = 0.f, num = 0.f;
    {
        float wgt = __expf(eself - m);
        den += wgt; num += wgt * bf2f(h[(size_t)node * 80 + t]);
    }
    for (int j = o0; j < o1; ++j) {
        int sc = srcs[j];
        float wgt = __expf(lrelu(als[sc * 8 + hh] + ad) - m);
        den += wgt; num += wgt * bf2f(h[(size_t)sc * 80 + t]);
    }
    ha[(size_t)node * 80 + t] = f2bf(fmaxf(num / den + bias[t], 0.f));
}

__global__ __launch_bounds__(256) void k_gat2_al(
    const u16* __restrict__ h, const float* __restrict__ a_s,
    const float* __restrict__ a_d, float* als, float* ald)
{
    __shared__ float rs[256], rd[256];
    int node = blockIdx.x, t = threadIdx.x;
    float h0 = bf2f(h[(size_t)node * 512 + t]);
    float h1 = bf2f(h[(size_t)node * 512 + 256 + t]);
    rs[t] = h0 * a_s[t] + h1 * a_s[256 + t];
    rd[t] = h0 * a_d[t] + h1 * a_d[256 + t];
    __syncthreads();
    for (int o = 128; o > 0; o >>= 1) {
        if (t < o) { rs[t] += rs[t + o]; rd[t] += rd[t + o]; }
        __syncthreads();
    }
    if (t == 0) { als[node] = rs[0]; ald[node] = rd[0]; }
}

__global__ __launch_bounds__(256) void k_gat2_attn(
    const u16* __restrict__ h, const float* __restrict__ als,
    const float* __restrict__ ald, const float* __restrict__ bias,
    const int* __restrict__ offs, const int* __restrict__ srcs,
    const float* __restrict__ fusion_w, float* __restrict__ Y)
{
    int node = blockIdx.x;
    int t = threadIdx.x;
    float w2 = fusion_w[2];
    int o0 = offs[node], o1 = offs[node + 1];
    float ad = ald[node];
    float eself = lrelu(als[node] + ad);
    float m = eself;
    for (int j = o0; j < o1; ++j) m = fmaxf(m, lrelu(als[srcs[j]] + ad));
    float den = 0.f, n0 = 0.f, n1 = 0.f;
    {
        float wgt = __expf(eself - m);
        den += wgt;
        n0 += wgt * bf2f(h[(size_t)node * 512 + t]);
        n1 += wgt * bf2f(h[(size_t)node * 512 + 256 + t]);
    }
    for (int j = o0; j < o1; ++j) {
        int sc = srcs[j];
        float wgt = __expf(lrelu(als[sc] + ad) - m);
        den += wgt;
        n0 += wgt * bf2f(h[(size_t)sc * 512 + t]);
        n1 += wgt * bf2f(h[(size_t)sc * 512 + 256 + t]);
    }
    Y[(size_t)node * 512 + t]       += w2 * (n0 / den + bias[t]);
    Y[(size_t)node * 512 + 256 + t] += w2 * (n1 / den + bias[256 + t]);
}

// ---------------------------------------------------------------------------
// BatchNorm + final
// ---------------------------------------------------------------------------
__global__ __launch_bounds__(256) void k_bn_stats(const float* __restrict__ Y,
                                                  float* ssum, float* ssq) {
    int t = threadIdx.x;
    int b = blockIdx.x;
    int r0 = b * 40, r1 = r0 + 40;
    if (r1 > NN) r1 = NN;
    float s0 = 0, s1 = 0, q0 = 0, q1 = 0;
    for (int r = r0; r < r1; ++r) {
        float v0 = Y[(size_t)r * 512 + t];
        float v1 = Y[(size_t)r * 512 + 256 + t];
        s0 += v0; q0 += v0 * v0; s1 += v1; q1 += v1 * v1;
    }
    atomicAdd(&ssum[t], s0); atomicAdd(&ssum[256 + t], s1);
    atomicAdd(&ssq[t], q0);  atomicAdd(&ssq[256 + t], q1);
}

__global__ void k_bn_final(const float* ssum, const float* ssq, float* mu, float* inv) {
    int c = blockIdx.x * 256 + threadIdx.x;
    if (c < 512) {
        float m = ssum[c] / (float)NN;
        float v = ssq[c] / (float)NN - m * m;
        mu[c] = m;
        inv[c] = rsqrtf(v + 1e-5f);
    }
}

// k_final with bf16 y2 (halved gather traffic)
__global__ __launch_bounds__(256) void k_final(
    const u16* __restrict__ y2, const int* __restrict__ EI,
    const int* __restrict__ tid, const float* __restrict__ fcW,
    const float* __restrict__ fcb, float* __restrict__ out)
{
    int pair = blockIdx.x * 4 + (threadIdx.x >> 6);
    int lane = threadIdx.x & 63;
    if (pair >= NT) return;
    int eid = tid[pair];
    int a = EI[eid], b = EI[NE + eid];
    float acc[7] = {};
    for (int c = lane; c < 512; c += 64) {
        float v = bf2f(y2[(size_t)a * 512 + c]) * bf2f(y2[(size_t)b * 512 + c]);
        #pragma unroll
        for (int j = 0; j < 7; ++j) acc[j] = fmaf(v, fcW[c * 7 + j], acc[j]);
    }
    for (int o = 32; o > 0; o >>= 1) {
        #pragma unroll
        for (int j = 0; j < 7; ++j) acc[j] += __shfl_down(acc[j], o);
    }
    if (lane == 0) {
        #pragma unroll
        for (int j = 0; j < 7; ++j) out[(size_t)pair * 7 + j] = acc[j] + fcb[j];
    }
}

// ---------------------------------------------------------------------------
extern "C" void kernel_launch(void* const* d_in, const int* in_sizes, int n_in,
                              void* d_out, int out_size, void* d_ws, size_t ws_size,
                              hipStream_t stream)
{
    (void)in_sizes; (void)n_in; (void)out_size; (void)ws_size;
    const float* x        = (const float*)d_in[0];
    const int*   EI       = (const int*)d_in[1];
    const int*   tid      = (const int*)d_in[2];
    const float* Wp1      = (const float*)d_in[3];
    const float* bp1      = (const float*)d_in[4];
    const float* Wp2      = (const float*)d_in[5];
    const float* bp2      = (const float*)d_in[6];
    const float* Wp3      = (const float*)d_in[7];
    const float* bp3      = (const float*)d_in[8];
    const float* sage1_Wl = (const float*)d_in[9];
    const float* sage1_bl = (const float*)d_in[10];
    const float* sage1_Wr = (const float*)d_in[11];
    const float* sage2_Wl = (const float*)d_in[12];
    const float* sage2_bl = (const float*)d_in[13];
    const float* sage2_Wr = (const float*)d_in[14];
    const float* gin1_W1  = (const float*)d_in[15];
    const float* gin1_b1  = (const float*)d_in[16];
    const float* gin1_W2  = (const float*)d_in[17];
    const float* gin1_b2  = (const float*)d_in[18];
    const float* gin2_W1  = (const float*)d_in[19];
    const float* gin2_b1  = (const float*)d_in[20];
    const float* gin2_W2  = (const float*)d_in[21];
    const float* gin2_b2  = (const float*)d_in[22];
    const float* gin_lin_W= (const float*)d_in[23];
    const float* gin_lin_b= (const float*)d_in[24];
    const float* gat1_W   = (const float*)d_in[25];
    const float* gat1_as  = (const float*)d_in[26];
    const float* gat1_ad  = (const float*)d_in[27];
    const float* gat1_b   = (const float*)d_in[28];
    const float* gat2_W   = (const float*)d_in[29];
    const float* gat2_as  = (const float*)d_in[30];
    const float* gat2_ad  = (const float*)d_in[31];
    const float* gat2_b   = (const float*)d_in[32];
    const float* fusion_w = (const float*)d_in[33];
    const float* lin1_W   = (const float*)d_in[34];
    const float* lin1_b   = (const float*)d_in[35];
    const float* lin2_W   = (const float*)d_in[36];
    const float* lin2_b   = (const float*)d_in[37];
    const float* fc2_W    = (const float*)d_in[38];
    const float* fc2_b    = (const float*)d_in[39];

    char* base = (char*)d_ws;
    // R0 region: aliased buffers with disjoint lifetimes
    u16* mean1 = (u16*)base;                       // [0, 5.12M)
    u16* agg1  = (u16*)(base + 5120000);           // [5.12M,10.24M)
    u16* h2b   = (u16*)base;                       // [0,10.24M)   gat2
    u16* y1b   = (u16*)(base + 20480000);          // [20.48,30.72M)
    u16* y2b   = (u16*)base;                       // [0,10.24M)   after h2b dead
    size_t off = 40960000;
    u16* featb = (u16*)(base + off); off += 5120000;
    u16* hsb   = (u16*)(base + off); off += 2560000;
    u16* mean2 = (u16*)(base + off); off += 2560000;
    u16* g1    = (u16*)(base + off); off += 2560000;
    u16* g2    = (u16*)(base + off); off += 2560000;
    u16* hgat  = (u16*)(base + off); off += 1600000;
    u16* hab   = (u16*)(base + off); off += 1600000;
    float* Y   = (float*)(base + off); off += 20480000;
    float* als1 = (float*)(base + off); off += 320000;
    float* ald1 = (float*)(base + off); off += 320000;
    float* als2 = (float*)(base + off); off += 40000;
    float* ald2 = (float*)(base + off); off += 40000;
    float* ssum = (float*)(base + off); off += 2048;
    float* ssq  = (float*)(base + off); off += 2048;
    float* mu   = (float*)(base + off); off += 2048;
    float* inv  = (float*)(base + off); off += 2048;
    int* counts = (int*)(base + off); off += 40000;
    int* offs   = (int*)(base + off); off += 40016;
    int* cursor = (int*)(base + off); off += 40000;
    int* csrc   = (int*)(base + off); off += 640000;
    u16* W1f    = (u16*)(base + off); off += 4096;
    u16* W2f    = (u16*)(base + off); off += 16384;
    u16* W3f    = (u16*)(base + off); off += 65536;
    u16* s1lf   = (u16*)(base + off); off += 65536;   // 256x128
    u16* s1rf   = (u16*)(base + off); off += 65536;
    u16* g1w1f  = (u16*)(base + off); off += 65536;   // 256x128
    u16* g1w2f  = (u16*)(base + off); off += 32768;   // 128x128
    u16* ga1f   = (u16*)(base + off); off += 40960;   // 256x80
    u16* s2lf   = (u16*)(base + off); off += 131072;  // 128x512
    u16* s2rf   = (u16*)(base + off); off += 131072;
    u16* g2w1f  = (u16*)(base + off); off += 32768;
    u16* g2w2f  = (u16*)(base + off); off += 32768;
    u16* glinf  = (u16*)(base + off); off += 131072;  // 128x512
    u16* ga2f   = (u16*)(base + off); off += 131072;  // 80(->128)x512
    u16* l1f    = (u16*)(base + off); off += 524288;  // 512x512
    u16* l2f    = (u16*)(base + off); off += 524288;

    k_init<<<40, 256, 0, stream>>>(counts, ssum, ssq);
    k_wfrag<<<128, 256, 0, stream>>>(Wp1, Wp2, Wp3, W1f, W2f, W3f);
    k_pack<<<256, 256, 0, stream>>>(sage1_Wl, s1lf, 256, 8);
    k_pack<<<256, 256, 0, stream>>>(sage1_Wr, s1rf, 256, 8);
    k_pack<<<256, 256, 0, stream>>>(gin1_W1,  g1w1f, 256, 8);
    k_pack<<<256, 256, 0, stream>>>(gin1_W2,  g1w2f, 128, 8);
    k_pack<<<256, 256, 0, stream>>>(gat1_W,   ga1f, 256, 5);
    k_pack<<<256, 256, 0, stream>>>(sage2_Wl, s2lf, 128, 32);
    k_pack<<<256, 256, 0, stream>>>(sage2_Wr, s2rf, 128, 32);
    k_pack<<<256, 256, 0, stream>>>(gin2_W1,  g2w1f, 128, 8);
    k_pack<<<256, 256, 0, stream>>>(gin2_W2,  g2w2f, 128, 8);
    k_pack<<<256, 256, 0, stream>>>(gin_lin_W, glinf, 128, 32);
    k_pack<<<256, 256, 0, stream>>>(gat2_W,   ga2f, 80, 32);
    k_pack<<<256, 256, 0, stream>>>(lin1_W,   l1f, 512, 32);
    k_pack<<<256, 256, 0, stream>>>(lin2_W,   l2f, 512, 32);

    k_pointnet_mfma<<<NN, 256, 0, stream>>>(x, W1f, bp1, W2f, bp2, W3f, bp3, featb);
    k_csr_count<<<(NE + 255) / 256, 256, 0, stream>>>(EI, counts);
    k_scan<<<1, 1024, 0, stream>>>(counts, offs, cursor);
    k_csr_scatter<<<(NE + 255) / 256, 256, 0, stream>>>(EI, cursor, csrc);

    dim3 gN128(4, 79), gN80(5, 79), gWide(4, 79);

    // fused aggregation on feat: one pass -> mean1 (SAGE1) + agg1 (GIN1)
    k_agg2same<128><<<NN, 128, 0, stream>>>((const u32*)featb, (u32*)mean1, (u32*)agg1,
                                            offs, csrc);

    // SAGE1: hs = relu(mean1@Wl + feat@Wr + bl)
    k_mm<2,1,1,0,0><<<gN128, 256, 0, stream>>>(mean1, featb, s1lf, s1rf, sage1_bl,
                                               256, 8, hsb, nullptr, 0, nullptr, nullptr);
    // GIN1
    k_mm<2,0,1,0,0><<<gN128, 256, 0, stream>>>(agg1, nullptr, g1w1f, nullptr, gin1_b1,
                                               256, 8, g1, nullptr, 0, nullptr, nullptr);
    k_mm<2,0,1,0,0><<<gN128, 256, 0, stream>>>(g1, nullptr, g1w2f, nullptr, gin1_b2,
                                               128, 8, g2, nullptr, 0, nullptr, nullptr);

    // fused second-hop aggregation: mean2 = mean(hsb), g1 = self+sum(g2)
    k_agg2two<64><<<NN, 64, 0, stream>>>((const u32*)hsb, (const u32*)g2,
                                         (u32*)mean2, (u32*)g1, offs, csrc);

    // GAT1
    k_mm<1,0,0,0,0><<<gN80, 256, 0, stream>>>(featb, nullptr, ga1f, nullptr, nullptr,
                                              256, 5, hgat, nullptr, 0, nullptr, nullptr);
    k_gat1_al<<<1250, 64, 0, stream>>>(hgat, gat1_as, gat1_ad, als1, ald1);
    k_gat1_attn<<<NN, 128, 0, stream>>>(hgat, als1, ald1, gat1_b, offs, csrc, hab);

    // SAGE2: Y = w0*(mean2@Wl + hs@Wr + bl)
    k_mm<8,1,0,1,0><<<gWide, 256, 0, stream>>>(mean2, hsb, s2lf, s2rf, sage2_bl,
                                               128, 32, Y, fusion_w, 0, nullptr, nullptr);
    // GIN2
    k_mm<2,0,1,0,0><<<gN128, 256, 0, stream>>>(g1, nullptr, g2w1f, nullptr, gin2_b1,
                                               128, 8, g2, nullptr, 0, nullptr, nullptr);
    k_mm<2,0,1,0,0><<<gN128, 256, 0, stream>>>(g2, nullptr, g2w2f, nullptr, gin2_b2,
                                               128, 8, g1, nullptr, 0, nullptr, nullptr);
    k_mm<8,0,0,2,0><<<gWide, 256, 0, stream>>>(g1, nullptr, glinf, nullptr, gin_lin_b,
                                               128, 32, Y, fusion_w, 1, nullptr, nullptr);
    // GAT2
    k_mm<8,0,0,0,0><<<gWide, 256, 0, stream>>>(hab, nullptr, ga2f, nullptr, nullptr,
                                               80, 32, h2b, nullptr, 0, nullptr, nullptr);
    k_gat2_al<<<NN, 256, 0, stream>>>(h2b, gat2_as, gat2_ad, als2, ald2);
    k_gat2_attn<<<NN, 256, 0, stream>>>(h2b, als2, ald2, gat2_b, offs, csrc, fusion_w, Y);

    // BN (stats only; apply fused into lin1 staging) + head
    k_bn_stats<<<250, 256, 0, stream>>>(Y, ssum, ssq);
    k_bn_final<<<2, 256, 0, stream>>>(ssum, ssq, mu, inv);
    k_mm<8,0,1,0,1><<<gWide, 256, 0, stream>>>((const u16*)Y, nullptr, l1f, nullptr, lin1_b,
                                               512, 32, y1b, nullptr, 0, mu, inv);
    k_mm<8,0,0,0,0><<<gWide, 256, 0, stream>>>(y1b, nullptr, l2f, nullptr, lin2_b,
                                               512, 32, y2b, nullptr, 0, nullptr, nullptr);

    k_final<<<(NT + 3) / 4, 256, 0, stream>>>(y2b, EI, tid, fc2_W, fc2_b, (float*)d_out);
}

// Round 13
// 562.953 us; speedup vs baseline: 1.1918x; 1.1918x over previous
//
#include <hip/hip_runtime.h>
#include <math.h>

#define NN 10000
#define NE 160000
#define NT 50000

typedef unsigned short u16;
typedef unsigned int u32;
typedef __attribute__((ext_vector_type(8))) short bf16x8;
typedef __attribute__((ext_vector_type(4))) float f32x4;

__device__ __forceinline__ float bf2f(u16 u) { return __uint_as_float(((u32)u) << 16); }
__device__ __forceinline__ u16 f2bf(float f) {
    u32 x = __float_as_uint(f);
    return (u16)((x + 0x7fffu + ((x >> 16) & 1u)) >> 16);
}
// HW packed f32->bf16 (RNE)
__device__ __forceinline__ u32 cvtpk(float a, float b) {
    u32 r;
    asm("v_cvt_pk_bf16_f32 %0, %1, %2" : "=v"(r) : "v"(a), "v"(b));
    return r;
}
__device__ __forceinline__ float lrelu(float x) { return x > 0.f ? x : 0.2f * x; }

#define MFMA16(a, b, c) __builtin_amdgcn_mfma_f32_16x16x32_bf16((a), (b), (c), 0, 0, 0)

// ---------------------------------------------------------------------------
// Prep: pack pointnet W1/W2/W3 into MFMA B-fragment order.
// B-frag pack of W == A-frag pack of W^T (mirrored layouts), so W1f/W2f serve
// as A-operands for the swapped layers 1-2.
// ---------------------------------------------------------------------------
__global__ void k_wfrag(const float* __restrict__ W1, const float* __restrict__ W2,
                        const float* __restrict__ W3,
                        u16* __restrict__ W1f, u16* __restrict__ W2f, u16* __restrict__ W3f) {
    int i = blockIdx.x * 256 + threadIdx.x;
    if (i < 2048) {
        int e = i & 7, l = (i >> 3) & 63, nt = i >> 9;
        int k = (l >> 4) * 8 + e, c = nt * 16 + (l & 15);
        W1f[i] = (k < 16) ? f2bf(W1[k * 64 + c]) : (u16)0;
    }
    if (i < 8192) {
        int e = i & 7, l = (i >> 3) & 63, nt = (i >> 9) & 7, ks = i >> 12;
        int k = ks * 32 + (l >> 4) * 8 + e, c = nt * 16 + (l & 15);
        W2f[i] = f2bf(W2[k * 128 + c]);
    }
    if (i < 32768) {
        int e = i & 7, l = (i >> 3) & 63, nt = (i >> 9) & 15, ks = i >> 13;
        int k = ks * 32 + (l >> 4) * 8 + e, c = nt * 16 + (l & 15);
        W3f[i] = f2bf(W3[k * 256 + c]);
    }
}

// ---------------------------------------------------------------------------
// Generic weight pack: fp32 [K x M] -> bf16 frag order [ceil64(K)/32][M/16][64][8]
// ---------------------------------------------------------------------------
__global__ void k_pack(const float* __restrict__ W, u16* __restrict__ Wf, int K, int Mt) {
    int total = (((K + 63) & ~63) >> 5) * Mt * 512;
    for (int i = blockIdx.x * 256 + threadIdx.x; i < total; i += gridDim.x * 256) {
        int e = i & 7, l = (i >> 3) & 63, mt = (i >> 9) % Mt, kk = i / (Mt << 9);
        int k = (kk << 5) + ((l >> 4) << 3) + e;
        int c = (mt << 4) + (l & 15);
        Wf[i] = (k < K) ? f2bf(W[(size_t)k * (Mt << 4) + c]) : (u16)0;
    }
}

// ---------------------------------------------------------------------------
// MFMA point-net v2.1 (round-11 measured best, 151 µs): swapped layers 1-2
// (h1 in registers via 32 bpermutes), h2 through 32KB LDS with (row&15)<<3
// swizzle, layer 3 standard orientation. NOTE: v3 (all-swapped, layer-3
// B-frags via 64 more bpermutes) measured 273 µs — ds_bpermute chains
// serialize; do not revisit.
// ---------------------------------------------------------------------------
__global__ __launch_bounds__(256) void k_pointnet_mfma(
    const float* __restrict__ x,
    const u16* __restrict__ W1f, const float* __restrict__ b1,
    const u16* __restrict__ W2f, const float* __restrict__ b2,
    const u16* __restrict__ W3f, const float* __restrict__ b3,
    u16* __restrict__ featb)
{
    __shared__ __align__(16) u16 buf[16384];   // 32 KB: h2 [128 pt][128 ch] swizzled

    const int node = blockIdx.x;
    const int t = threadIdx.x;
    const int w = t >> 6;
    const int l = t & 63;
    const int lr = l & 15;
    const int lg = l >> 4;

    // ---- layer 1 (swapped): h1^T[ch=64][pt] for this wave's 32 pts --------
    u32 pk1[4][2][2];   // h1 bf16-packed: [cht][ptt][reg-pair]
    {
        union { u32 q[4]; bf16x8 v; } xb0, xb1;
        xb0.q[0] = xb0.q[1] = xb0.q[2] = xb0.q[3] = 0;
        xb1 = xb0;
        if (lg < 2) {
            const float* px = x + ((size_t)node * 128 + w * 32 + lr) * 16 + lg * 8;
            float4 f0 = *(const float4*)px;
            float4 f1 = *(const float4*)(px + 4);
            xb0.q[0] = cvtpk(f0.x, f0.y); xb0.q[1] = cvtpk(f0.z, f0.w);
            xb0.q[2] = cvtpk(f1.x, f1.y); xb0.q[3] = cvtpk(f1.z, f1.w);
            float4 g0 = *(const float4*)(px + 256);
            float4 g1 = *(const float4*)(px + 260);
            xb1.q[0] = cvtpk(g0.x, g0.y); xb1.q[1] = cvtpk(g0.z, g0.w);
            xb1.q[2] = cvtpk(g1.x, g1.y); xb1.q[3] = cvtpk(g1.z, g1.w);
        }
        #pragma unroll
        for (int cht = 0; cht < 4; ++cht) {
            f32x4 ci = *(const f32x4*)(b1 + cht * 16 + 4 * lg);  // bias along regs
            bf16x8 wf = *(const bf16x8*)(W1f + (cht * 64 + l) * 8);
            f32x4 a0 = MFMA16(wf, xb0.v, ci);
            f32x4 a1 = MFMA16(wf, xb1.v, ci);
            pk1[cht][0][0] = cvtpk(fmaxf(a0[0], 0.f), fmaxf(a0[1], 0.f));
            pk1[cht][0][1] = cvtpk(fmaxf(a0[2], 0.f), fmaxf(a0[3], 0.f));
            pk1[cht][1][0] = cvtpk(fmaxf(a1[0], 0.f), fmaxf(a1[1], 0.f));
            pk1[cht][1][1] = cvtpk(fmaxf(a1[2], 0.f), fmaxf(a1[3], 0.f));
        }
    }

    // ---- layer 2 (swapped): h2^T = W2^T @ h1^T, B-frags via shuffles ------
    {
        f32x4 acc2[8][2];
        #pragma unroll
        for (int mt = 0; mt < 8; ++mt) {
            f32x4 ci = *(const f32x4*)(b2 + mt * 16 + 4 * lg);
            acc2[mt][0] = ci;
            acc2[mt][1] = ci;
        }
        #pragma unroll
        for (int ks = 0; ks < 2; ++ks) {
            union { u32 q[4]; bf16x8 v; } B2[2];
            #pragma unroll
            for (int ptt = 0; ptt < 2; ++ptt) {
                #pragma unroll
                for (int j = 0; j < 4; ++j) {
                    int s = ((2 * (lg & 1) + (j >> 1)) << 4) + lr;
                    int lo = __shfl((int)pk1[2 * ks][ptt][j & 1], s);
                    int hi = __shfl((int)pk1[2 * ks + 1][ptt][j & 1], s);
                    B2[ptt].q[j] = (u32)((lg >> 1) ? hi : lo);
                }
            }
            #pragma unroll
            for (int mt = 0; mt < 8; ++mt) {
                bf16x8 af = *(const bf16x8*)(W2f + ((ks * 8 + mt) * 64 + l) * 8);
                acc2[mt][0] = MFMA16(af, B2[0].v, acc2[mt][0]);
                acc2[mt][1] = MFMA16(af, B2[1].v, acc2[mt][1]);
            }
        }
        // epilogue: h2 row-major [pt][ch], 4 consecutive ch per lane -> b64
        #pragma unroll
        for (int mt = 0; mt < 8; ++mt) {
            #pragma unroll
            for (int ptt = 0; ptt < 2; ++ptt) {
                int pt = w * 32 + ptt * 16 + lr;
                int ch0 = mt * 16 + 4 * lg;
                u32 q0 = cvtpk(fmaxf(acc2[mt][ptt][0], 0.f), fmaxf(acc2[mt][ptt][1], 0.f));
                u32 q1 = cvtpk(fmaxf(acc2[mt][ptt][2], 0.f), fmaxf(acc2[mt][ptt][3], 0.f));
                int idx = (pt * 128 + ch0) ^ ((pt & 15) << 3);
                *(uint2*)&buf[idx] = make_uint2(q0, q1);
            }
        }
    }
    __syncthreads();

    // ---------------- layer 3 + max-pool ----------
    {
        float pmax[4] = {0.f, 0.f, 0.f, 0.f};   // pmax>=0 subsumes relu
        #pragma unroll
        for (int half = 0; half < 2; ++half) {
            f32x4 acc3[4][4];
            #pragma unroll
            for (int nt = 0; nt < 4; ++nt) {
                float bv = b3[w * 64 + nt * 16 + lr];
                f32x4 ci = {bv, bv, bv, bv};
                #pragma unroll
                for (int mt = 0; mt < 4; ++mt) acc3[mt][nt] = ci;
            }
            #pragma unroll
            for (int ks = 0; ks < 4; ++ks) {
                bf16x8 bf_[4];
                #pragma unroll
                for (int nt = 0; nt < 4; ++nt)
                    bf_[nt] = *(const bf16x8*)(W3f + ((ks * 16 + w * 4 + nt) * 64 + l) * 8);
                #pragma unroll
                for (int mt = 0; mt < 4; ++mt) {
                    int row = half * 64 + mt * 16 + lr;
                    int elem = row * 128 + ks * 32 + lg * 8;
                    bf16x8 af = *(const bf16x8*)&buf[elem ^ ((row & 15) << 3)];
                    #pragma unroll
                    for (int nt = 0; nt < 4; ++nt)
                        acc3[mt][nt] = MFMA16(af, bf_[nt], acc3[mt][nt]);
                }
            }
            #pragma unroll
            for (int nt = 0; nt < 4; ++nt) {
                #pragma unroll
                for (int mt = 0; mt < 4; ++mt) {
                    pmax[nt] = fmaxf(fmaxf(pmax[nt], acc3[mt][nt][0]),
                                     fmaxf(acc3[mt][nt][1],
                                           fmaxf(acc3[mt][nt][2], acc3[mt][nt][3])));
                }
            }
        }
        #pragma unroll
        for (int nt = 0; nt < 4; ++nt) {
            pmax[nt] = fmaxf(pmax[nt], __shfl_xor(pmax[nt], 16));
            pmax[nt] = fmaxf(pmax[nt], __shfl_xor(pmax[nt], 32));
        }
        if (l < 16) {
            #pragma unroll
            for (int nt = 0; nt < 4; ++nt)
                featb[(size_t)node * 256 + w * 64 + nt * 16 + l] = f2bf(pmax[nt]);
        }
    }
}

// ---------------------------------------------------------------------------
// Generic bf16 MFMA GEMM (unchanged).
// ---------------------------------------------------------------------------
template<int CT, int DUAL, int RELU, int OUTM, int NORMA>
__global__ __launch_bounds__(256) void k_mm(
    const u16* __restrict__ A, const u16* __restrict__ A2,
    const u16* __restrict__ Bf, const u16* __restrict__ B2f,
    const float* __restrict__ bias, int K, int Mt,
    void* __restrict__ outp,
    const float* __restrict__ scale_ptr, int scale_idx,
    const float* __restrict__ mu, const float* __restrict__ inv)
{
    __shared__ u16 As[8192];
    __shared__ u16 As2[DUAL ? 8192 : 8];

    const int t = threadIdx.x;
    const int l = t & 63, lr = l & 15, lg = l >> 4;
    const int row0 = blockIdx.y << 7;
    const int ct0 = blockIdx.x * CT;
    const int m0 = (t >> 6) << 5;

    f32x4 acc[2][CT];
    #pragma unroll
    for (int nt = 0; nt < CT; ++nt) {
        float bv = bias ? bias[((ct0 + nt) << 4) + lr] : 0.f;
        f32x4 ci = {bv, bv, bv, bv};
        acc[0][nt] = ci;
        acc[1][nt] = ci;
    }

    const int KS = (K + 63) >> 6;
    for (int kblk = 0; kblk < KS; ++kblk) {
        const int k0 = kblk << 6;
        if (kblk) __syncthreads();
        #pragma unroll
        for (int j = 0; j < 4; ++j) {
            int si = t + (j << 8);
            int row = si >> 3, seg = si & 7;
            int gr = row0 + row;
            int kb = k0 + (seg << 3);
            int soff = ((row << 6) + (seg << 3)) ^ ((row & 7) << 3);
            if (NORMA) {
                u32 q0 = 0, q1 = 0, q2 = 0, q3 = 0;
                if (gr < NN) {
                    const float* Af = (const float*)A;
                    float4 f0 = *(const float4*)(Af + (size_t)gr * K + kb);
                    float4 f1 = *(const float4*)(Af + (size_t)gr * K + kb + 4);
                    q0 = cvtpk((f0.x - mu[kb+0]) * inv[kb+0], (f0.y - mu[kb+1]) * inv[kb+1]);
                    q1 = cvtpk((f0.z - mu[kb+2]) * inv[kb+2], (f0.w - mu[kb+3]) * inv[kb+3]);
                    q2 = cvtpk((f1.x - mu[kb+4]) * inv[kb+4], (f1.y - mu[kb+5]) * inv[kb+5]);
                    q3 = cvtpk((f1.z - mu[kb+6]) * inv[kb+6], (f1.w - mu[kb+7]) * inv[kb+7]);
                }
                u32* dst = (u32*)&As[soff];
                dst[0] = q0; dst[1] = q1; dst[2] = q2; dst[3] = q3;
            } else {
                bf16x8 v = {0,0,0,0,0,0,0,0};
                bf16x8 v2 = {0,0,0,0,0,0,0,0};
                if (gr < NN) {
                    if (kb + 8 <= K) {
                        v = *(const bf16x8*)(A + (size_t)gr * K + kb);
                        if (DUAL) v2 = *(const bf16x8*)(A2 + (size_t)gr * K + kb);
                    } else {
                        #pragma unroll
                        for (int e = 0; e < 8; ++e) if (kb + e < K) {
                            v[e] = (short)A[(size_t)gr * K + kb + e];
                            if (DUAL) v2[e] = (short)A2[(size_t)gr * K + kb + e];
                        }
                    }
                }
                *(bf16x8*)&As[soff] = v;
                if (DUAL) *(bf16x8*)&As2[soff] = v2;
            }
        }
        __syncthreads();
        #pragma unroll
        for (int ks = 0; ks < 2; ++ks) {
            const int kk = (k0 >> 5) + ks;
            bf16x8 bfr[CT];
            #pragma unroll
            for (int nt = 0; nt < CT; ++nt)
                bfr[nt] = *(const bf16x8*)(Bf + (((size_t)kk * Mt + ct0 + nt) << 9) + (l << 3));
            #pragma unroll
            for (int mt = 0; mt < 2; ++mt) {
                int row = m0 + (mt << 4) + lr;
                int soff = ((row << 6) + (ks << 5) + (lg << 3)) ^ ((row & 7) << 3);
                bf16x8 af = *(const bf16x8*)&As[soff];
                #pragma unroll
                for (int nt = 0; nt < CT; ++nt)
                    acc[mt][nt] = MFMA16(af, bfr[nt], acc[mt][nt]);
            }
            if (DUAL) {
                bf16x8 bfr2[CT];
                #pragma unroll
                for (int nt = 0; nt < CT; ++nt)
                    bfr2[nt] = *(const bf16x8*)(B2f + (((size_t)kk * Mt + ct0 + nt) << 9) + (l << 3));
                #pragma unroll
                for (int mt = 0; mt < 2; ++mt) {
                    int row = m0 + (mt << 4) + lr;
                    int soff = ((row << 6) + (ks << 5) + (lg << 3)) ^ ((row & 7) << 3);
                    bf16x8 af2 = *(const bf16x8*)&As2[soff];
                    #pragma unroll
                    for (int nt = 0; nt < CT; ++nt)
                        acc[mt][nt] = MFMA16(af2, bfr2[nt], acc[mt][nt]);
                }
            }
        }
    }

    float scale = 1.f;
    if (OUTM == 1 || OUTM == 2) scale = scale_ptr[scale_idx];
    const int M = Mt << 4;
    #pragma unroll
    for (int mt = 0; mt < 2; ++mt) {
        #pragma unroll
        for (int nt = 0; nt < CT; ++nt) {
            int col = ((ct0 + nt) << 4) + lr;
            #pragma unroll
            for (int r = 0; r < 4; ++r) {
                int grow = row0 + m0 + (mt << 4) + (lg << 2) + r;
                if (grow >= NN) continue;
                float v = acc[mt][nt][r];
                if (RELU) v = fmaxf(v, 0.f);
                size_t o = (size_t)grow * M + col;
                if (OUTM == 0) ((u16*)outp)[o] = f2bf(v);
                else if (OUTM == 1) ((float*)outp)[o] = scale * v;
                else if (OUTM == 2) ((float*)outp)[o] += scale * v;
                else ((float*)outp)[o] = v;
            }
        }
    }
}

// ---------------------------------------------------------------------------
// CSR build
// ---------------------------------------------------------------------------
__global__ void k_init(int* counts, float* s1, float* s2) {
    int i = blockIdx.x * 256 + threadIdx.x;
    if (i < NN) counts[i] = 0;
    if (i < 512) { s1[i] = 0.f; s2[i] = 0.f; }
}

__global__ void k_csr_count(const int* __restrict__ EI, int* counts) {
    int e = blockIdx.x * 256 + threadIdx.x;
    if (e < NE) atomicAdd(&counts[EI[NE + e]], 1);
}

__global__ __launch_bounds__(1024) void k_scan(const int* __restrict__ counts,
                                               int* offs, int* cursor) {
    __shared__ int buf[1024];
    int t = threadIdx.x;
    int carry = 0;
    for (int chunk = 0; chunk < (NN + 1023) / 1024; ++chunk) {
        int i = chunk * 1024 + t;
        int v = (i < NN) ? counts[i] : 0;
        buf[t] = v;
        __syncthreads();
        for (int o = 1; o < 1024; o <<= 1) {
            int xv = (t >= o) ? buf[t - o] : 0;
            __syncthreads();
            buf[t] += xv;
            __syncthreads();
        }
        int excl = buf[t] - v;
        if (i < NN) { offs[i] = carry + excl; cursor[i] = carry + excl; }
        carry += buf[1023];
        __syncthreads();
    }
    if (t == 0) offs[NN] = carry;
}

__global__ void k_csr_scatter(const int* __restrict__ EI, int* cursor, int* csrc) {
    int e = blockIdx.x * 256 + threadIdx.x;
    if (e < NE) {
        int d = EI[NE + e];
        int pos = atomicAdd(&cursor[d], 1);
        csrc[pos] = EI[e];
    }
}

// ---------------------------------------------------------------------------
// Fused aggregations (round-11 versions).
// ---------------------------------------------------------------------------
template<int WU>
__global__ void k_agg2same(const u32* __restrict__ in, u32* __restrict__ out_mean,
                           u32* __restrict__ out_agg,
                           const int* __restrict__ offs, const int* __restrict__ srcs)
{
    int node = blockIdx.x;
    int c = threadIdx.x;
    int o0 = offs[node], o1 = offs[node + 1];
    float s0 = 0.f, s1 = 0.f;
    for (int j = o0; j < o1; ++j) {
        u32 v = in[(size_t)srcs[j] * WU + c];
        s0 += bf2f((u16)(v & 0xffff));
        s1 += bf2f((u16)(v >> 16));
    }
    int d = o1 - o0;
    float r = 1.f / (float)(d > 0 ? d : 1);
    out_mean[(size_t)node * WU + c] = cvtpk(s0 * r, s1 * r);
    u32 v = in[(size_t)node * WU + c];
    out_agg[(size_t)node * WU + c] = cvtpk(s0 + bf2f((u16)(v & 0xffff)),
                                           s1 + bf2f((u16)(v >> 16)));
}

template<int WU>
__global__ void k_agg2two(const u32* __restrict__ inM, const u32* __restrict__ inS,
                          u32* __restrict__ outM, u32* __restrict__ outS,
                          const int* __restrict__ offs, const int* __restrict__ srcs)
{
    int node = blockIdx.x;
    int c = threadIdx.x;
    int o0 = offs[node], o1 = offs[node + 1];
    float m0 = 0.f, m1 = 0.f, s0 = 0.f, s1 = 0.f;
    for (int j = o0; j < o1; ++j) {
        int sc = srcs[j];
        u32 a = inM[(size_t)sc * WU + c];
        u32 b = inS[(size_t)sc * WU + c];
        m0 += bf2f((u16)(a & 0xffff)); m1 += bf2f((u16)(a >> 16));
        s0 += bf2f((u16)(b & 0xffff)); s1 += bf2f((u16)(b >> 16));
    }
    int d = o1 - o0;
    float r = 1.f / (float)(d > 0 ? d : 1);
    outM[(size_t)node * WU + c] = cvtpk(m0 * r, m1 * r);
    u32 v = inS[(size_t)node * WU + c];
    outS[(size_t)node * WU + c] = cvtpk(s0 + bf2f((u16)(v & 0xffff)),
                                        s1 + bf2f((u16)(v >> 16)));
}

// ---------------------------------------------------------------------------
// GAT (bf16 features)
// ---------------------------------------------------------------------------
__global__ void k_gat1_al(const u16* __restrict__ h, const float* __restrict__ a_s,
                          const float* __restrict__ a_d, float* als, float* ald) {
    int idx = blockIdx.x * 64 + threadIdx.x;
    if (idx >= NN * 8) return;
    int node = idx >> 3, hh = idx & 7;
    float s = 0.f, d = 0.f;
    #pragma unroll
    for (int c = 0; c < 10; ++c) {
        float hv = bf2f(h[node * 80 + hh * 10 + c]);
        s = fmaf(hv, a_s[hh * 10 + c], s);
        d = fmaf(hv, a_d[hh * 10 + c], d);
    }
    als[idx] = s; ald[idx] = d;
}

__global__ __launch_bounds__(128) void k_gat1_attn(
    const u16* __restrict__ h, const float* __restrict__ als,
    const float* __restrict__ ald, const float* __restrict__ bias,
    const int* __restrict__ offs, const int* __restrict__ srcs,
    u16* __restrict__ ha)
{
    int node = blockIdx.x;
    int t = threadIdx.x;
    if (t >= 80) return;
    int hh = t / 10;
    int o0 = offs[node], o1 = offs[node + 1];
    float ad = ald[node * 8 + hh];
    float eself = lrelu(als[node * 8 + hh] + ad);
    float m = eself;
    for (int j = o0; j < o1; ++j)
        m = fmaxf(m, lrelu(als[srcs[j] * 8 + hh] + ad));
    float den = 0.f, num = 0.f;
    {
        float wgt = __expf(eself - m);
        den += wgt; num += wgt * bf2f(h[(size_t)node * 80 + t]);
    }
    for (int j = o0; j < o1; ++j) {
        int sc = srcs[j];
        float wgt = __expf(lrelu(als[sc * 8 + hh] + ad) - m);
        den += wgt; num += wgt * bf2f(h[(size_t)sc * 80 + t]);
    }
    ha[(size_t)node * 80 + t] = f2bf(fmaxf(num / den + bias[t], 0.f));
}

__global__ __launch_bounds__(256) void k_gat2_al(
    const u16* __restrict__ h, const float* __restrict__ a_s,
    const float* __restrict__ a_d, float* als, float* ald)
{
    __shared__ float rs[256], rd[256];
    int node = blockIdx.x, t = threadIdx.x;
    float h0 = bf2f(h[(size_t)node * 512 + t]);
    float h1 = bf2f(h[(size_t)node * 512 + 256 + t]);
    rs[t] = h0 * a_s[t] + h1 * a_s[256 + t];
    rd[t] = h0 * a_d[t] + h1 * a_d[256 + t];
    __syncthreads();
    for (int o = 128; o > 0; o >>= 1) {
        if (t < o) { rs[t] += rs[t + o]; rd[t] += rd[t + o]; }
        __syncthreads();
    }
    if (t == 0) { als[node] = rs[0]; ald[node] = rd[0]; }
}

__global__ __launch_bounds__(256) void k_gat2_attn(
    const u16* __restrict__ h, const float* __restrict__ als,
    const float* __restrict__ ald, const float* __restrict__ bias,
    const int* __restrict__ offs, const int* __restrict__ srcs,
    const float* __restrict__ fusion_w, float* __restrict__ Y)
{
    int node = blockIdx.x;
    int t = threadIdx.x;
    float w2 = fusion_w[2];
    int o0 = offs[node], o1 = offs[node + 1];
    float ad = ald[node];
    float eself = lrelu(als[node] + ad);
    float m = eself;
    for (int j = o0; j < o1; ++j) m = fmaxf(m, lrelu(als[srcs[j]] + ad));
    float den = 0.f, n0 = 0.f, n1 = 0.f;
    {
        float wgt = __expf(eself - m);
        den += wgt;
        n0 += wgt * bf2f(h[(size_t)node * 512 + t]);
        n1 += wgt * bf2f(h[(size_t)node * 512 + 256 + t]);
    }
    for (int j = o0; j < o1; ++j) {
        int sc = srcs[j];
        float wgt = __expf(lrelu(als[sc] + ad) - m);
        den += wgt;
        n0 += wgt * bf2f(h[(size_t)sc * 512 + t]);
        n1 += wgt * bf2f(h[(size_t)sc * 512 + 256 + t]);
    }
    Y[(size_t)node * 512 + t]       += w2 * (n0 / den + bias[t]);
    Y[(size_t)node * 512 + 256 + t] += w2 * (n1 / den + bias[256 + t]);
}

// ---------------------------------------------------------------------------
// BatchNorm + final
// ---------------------------------------------------------------------------
__global__ __launch_bounds__(256) void k_bn_stats(const float* __restrict__ Y,
                                                  float* ssum, float* ssq) {
    int t = threadIdx.x;
    int b = blockIdx.x;
    int r0 = b * 40, r1 = r0 + 40;
    if (r1 > NN) r1 = NN;
    float s0 = 0, s1 = 0, q0 = 0, q1 = 0;
    for (int r = r0; r < r1; ++r) {
        float v0 = Y[(size_t)r * 512 + t];
        float v1 = Y[(size_t)r * 512 + 256 + t];
        s0 += v0; q0 += v0 * v0; s1 += v1; q1 += v1 * v1;
    }
    atomicAdd(&ssum[t], s0); atomicAdd(&ssum[256 + t], s1);
    atomicAdd(&ssq[t], q0);  atomicAdd(&ssq[256 + t], q1);
}

__global__ void k_bn_final(const float* ssum, const float* ssq, float* mu, float* inv) {
    int c = blockIdx.x * 256 + threadIdx.x;
    if (c < 512) {
        float m = ssum[c] / (float)NN;
        float v = ssq[c] / (float)NN - m * m;
        mu[c] = m;
        inv[c] = rsqrtf(v + 1e-5f);
    }
}

// k_final with bf16 y2 (halved gather traffic)
__global__ __launch_bounds__(256) void k_final(
    const u16* __restrict__ y2, const int* __restrict__ EI,
    const int* __restrict__ tid, const float* __restrict__ fcW,
    const float* __restrict__ fcb, float* __restrict__ out)
{
    int pair = blockIdx.x * 4 + (threadIdx.x >> 6);
    int lane = threadIdx.x & 63;
    if (pair >= NT) return;
    int eid = tid[pair];
    int a = EI[eid], b = EI[NE + eid];
    float acc[7] = {};
    for (int c = lane; c < 512; c += 64) {
        float v = bf2f(y2[(size_t)a * 512 + c]) * bf2f(y2[(size_t)b * 512 + c]);
        #pragma unroll
        for (int j = 0; j < 7; ++j) acc[j] = fmaf(v, fcW[c * 7 + j], acc[j]);
    }
    for (int o = 32; o > 0; o >>= 1) {
        #pragma unroll
        for (int j = 0; j < 7; ++j) acc[j] += __shfl_down(acc[j], o);
    }
    if (lane == 0) {
        #pragma unroll
        for (int j = 0; j < 7; ++j) out[(size_t)pair * 7 + j] = acc[j] + fcb[j];
    }
}

// ---------------------------------------------------------------------------
extern "C" void kernel_launch(void* const* d_in, const int* in_sizes, int n_in,
                              void* d_out, int out_size, void* d_ws, size_t ws_size,
                              hipStream_t stream)
{
    (void)in_sizes; (void)n_in; (void)out_size; (void)ws_size;
    const float* x        = (const float*)d_in[0];
    const int*   EI       = (const int*)d_in[1];
    const int*   tid      = (const int*)d_in[2];
    const float* Wp1      = (const float*)d_in[3];
    const float* bp1      = (const float*)d_in[4];
    const float* Wp2      = (const float*)d_in[5];
    const float* bp2      = (const float*)d_in[6];
    const float* Wp3      = (const float*)d_in[7];
    const float* bp3      = (const float*)d_in[8];
    const float* sage1_Wl = (const float*)d_in[9];
    const float* sage1_bl = (const float*)d_in[10];
    const float* sage1_Wr = (const float*)d_in[11];
    const float* sage2_Wl = (const float*)d_in[12];
    const float* sage2_bl = (const float*)d_in[13];
    const float* sage2_Wr = (const float*)d_in[14];
    const float* gin1_W1  = (const float*)d_in[15];
    const float* gin1_b1  = (const float*)d_in[16];
    const float* gin1_W2  = (const float*)d_in[17];
    const float* gin1_b2  = (const float*)d_in[18];
    const float* gin2_W1  = (const float*)d_in[19];
    const float* gin2_b1  = (const float*)d_in[20];
    const float* gin2_W2  = (const float*)d_in[21];
    const float* gin2_b2  = (const float*)d_in[22];
    const float* gin_lin_W= (const float*)d_in[23];
    const float* gin_lin_b= (const float*)d_in[24];
    const float* gat1_W   = (const float*)d_in[25];
    const float* gat1_as  = (const float*)d_in[26];
    const float* gat1_ad  = (const float*)d_in[27];
    const float* gat1_b   = (const float*)d_in[28];
    const float* gat2_W   = (const float*)d_in[29];
    const float* gat2_as  = (const float*)d_in[30];
    const float* gat2_ad  = (const float*)d_in[31];
    const float* gat2_b   = (const float*)d_in[32];
    const float* fusion_w = (const float*)d_in[33];
    const float* lin1_W   = (const float*)d_in[34];
    const float* lin1_b   = (const float*)d_in[35];
    const float* lin2_W   = (const float*)d_in[36];
    const float* lin2_b   = (const float*)d_in[37];
    const float* fc2_W    = (const float*)d_in[38];
    const float* fc2_b    = (const float*)d_in[39];

    char* base = (char*)d_ws;
    // R0 region: aliased buffers with disjoint lifetimes
    u16* mean1 = (u16*)base;                       // [0, 5.12M)
    u16* agg1  = (u16*)(base + 5120000);           // [5.12M,10.24M)
    u16* h2b   = (u16*)base;                       // [0,10.24M)   gat2
    u16* y1b   = (u16*)(base + 20480000);          // [20.48,30.72M)
    u16* y2b   = (u16*)base;                       // [0,10.24M)   after h2b dead
    size_t off = 40960000;
    u16* featb = (u16*)(base + off); off += 5120000;
    u16* hsb   = (u16*)(base + off); off += 2560000;
    u16* mean2 = (u16*)(base + off); off += 2560000;
    u16* g1    = (u16*)(base + off); off += 2560000;
    u16* g2    = (u16*)(base + off); off += 2560000;
    u16* hgat  = (u16*)(base + off); off += 1600000;
    u16* hab   = (u16*)(base + off); off += 1600000;
    float* Y   = (float*)(base + off); off += 20480000;
    float* als1 = (float*)(base + off); off += 320000;
    float* ald1 = (float*)(base + off); off += 320000;
    float* als2 = (float*)(base + off); off += 40000;
    float* ald2 = (float*)(base + off); off += 40000;
    float* ssum = (float*)(base + off); off += 2048;
    float* ssq  = (float*)(base + off); off += 2048;
    float* mu   = (float*)(base + off); off += 2048;
    float* inv  = (float*)(base + off); off += 2048;
    int* counts = (int*)(base + off); off += 40000;
    int* offs   = (int*)(base + off); off += 40016;
    int* cursor = (int*)(base + off); off += 40000;
    int* csrc   = (int*)(base + off); off += 640000;
    u16* W1f    = (u16*)(base + off); off += 4096;
    u16* W2f    = (u16*)(base + off); off += 16384;
    u16* W3f    = (u16*)(base + off); off += 65536;
    u16* s1lf   = (u16*)(base + off); off += 65536;   // 256x128
    u16* s1rf   = (u16*)(base + off); off += 65536;
    u16* g1w1f  = (u16*)(base + off); off += 65536;   // 256x128
    u16* g1w2f  = (u16*)(base + off); off += 32768;   // 128x128
    u16* ga1f   = (u16*)(base + off); off += 40960;   // 256x80
    u16* s2lf   = (u16*)(base + off); off += 131072;  // 128x512
    u16* s2rf   = (u16*)(base + off); off += 131072;
    u16* g2w1f  = (u16*)(base + off); off += 32768;
    u16* g2w2f  = (u16*)(base + off); off += 32768;
    u16* glinf  = (u16*)(base + off); off += 131072;  // 128x512
    u16* ga2f   = (u16*)(base + off); off += 131072;  // 80(->128)x512
    u16* l1f    = (u16*)(base + off); off += 524288;  // 512x512
    u16* l2f    = (u16*)(base + off); off += 524288;

    k_init<<<40, 256, 0, stream>>>(counts, ssum, ssq);
    k_wfrag<<<128, 256, 0, stream>>>(Wp1, Wp2, Wp3, W1f, W2f, W3f);
    k_pack<<<256, 256, 0, stream>>>(sage1_Wl, s1lf, 256, 8);
    k_pack<<<256, 256, 0, stream>>>(sage1_Wr, s1rf, 256, 8);
    k_pack<<<256, 256, 0, stream>>>(gin1_W1,  g1w1f, 256, 8);
    k_pack<<<256, 256, 0, stream>>>(gin1_W2,  g1w2f, 128, 8);
    k_pack<<<256, 256, 0, stream>>>(gat1_W,   ga1f, 256, 5);
    k_pack<<<256, 256, 0, stream>>>(sage2_Wl, s2lf, 128, 32);
    k_pack<<<256, 256, 0, stream>>>(sage2_Wr, s2rf, 128, 32);
    k_pack<<<256, 256, 0, stream>>>(gin2_W1,  g2w1f, 128, 8);
    k_pack<<<256, 256, 0, stream>>>(gin2_W2,  g2w2f, 128, 8);
    k_pack<<<256, 256, 0, stream>>>(gin_lin_W, glinf, 128, 32);
    k_pack<<<256, 256, 0, stream>>>(gat2_W,   ga2f, 80, 32);
    k_pack<<<256, 256, 0, stream>>>(lin1_W,   l1f, 512, 32);
    k_pack<<<256, 256, 0, stream>>>(lin2_W,   l2f, 512, 32);

    k_pointnet_mfma<<<NN, 256, 0, stream>>>(x, W1f, bp1, W2f, bp2, W3f, bp3, featb);
    k_csr_count<<<(NE + 255) / 256, 256, 0, stream>>>(EI, counts);
    k_scan<<<1, 1024, 0, stream>>>(counts, offs, cursor);
    k_csr_scatter<<<(NE + 255) / 256, 256, 0, stream>>>(EI, cursor, csrc);

    dim3 gN128(4, 79), gN80(5, 79), gWide(4, 79);

    // fused aggregation on feat: one pass -> mean1 (SAGE1) + agg1 (GIN1)
    k_agg2same<128><<<NN, 128, 0, stream>>>((const u32*)featb, (u32*)mean1, (u32*)agg1,
                                            offs, csrc);

    // SAGE1: hs = relu(mean1@Wl + feat@Wr + bl)
    k_mm<2,1,1,0,0><<<gN128, 256, 0, stream>>>(mean1, featb, s1lf, s1rf, sage1_bl,
                                               256, 8, hsb, nullptr, 0, nullptr, nullptr);
    // GIN1
    k_mm<2,0,1,0,0><<<gN128, 256, 0, stream>>>(agg1, nullptr, g1w1f, nullptr, gin1_b1,
                                               256, 8, g1, nullptr, 0, nullptr, nullptr);
    k_mm<2,0,1,0,0><<<gN128, 256, 0, stream>>>(g1, nullptr, g1w2f, nullptr, gin1_b2,
                                               128, 8, g2, nullptr, 0, nullptr, nullptr);

    // fused second-hop aggregation: mean2 = mean(hsb), g1 = self+sum(g2)
    k_agg2two<64><<<NN, 64, 0, stream>>>((const u32*)hsb, (const u32*)g2,
                                         (u32*)mean2, (u32*)g1, offs, csrc);

    // GAT1
    k_mm<1,0,0,0,0><<<gN80, 256, 0, stream>>>(featb, nullptr, ga1f, nullptr, nullptr,
                                              256, 5, hgat, nullptr, 0, nullptr, nullptr);
    k_gat1_al<<<1250, 64, 0, stream>>>(hgat, gat1_as, gat1_ad, als1, ald1);
    k_gat1_attn<<<NN, 128, 0, stream>>>(hgat, als1, ald1, gat1_b, offs, csrc, hab);

    // SAGE2: Y = w0*(mean2@Wl + hs@Wr + bl)
    k_mm<8,1,0,1,0><<<gWide, 256, 0, stream>>>(mean2, hsb, s2lf, s2rf, sage2_bl,
                                               128, 32, Y, fusion_w, 0, nullptr, nullptr);
    // GIN2
    k_mm<2,0,1,0,0><<<gN128, 256, 0, stream>>>(g1, nullptr, g2w1f, nullptr, gin2_b1,
                                               128, 8, g2, nullptr, 0, nullptr, nullptr);
    k_mm<2,0,1,0,0><<<gN128, 256, 0, stream>>>(g2, nullptr, g2w2f, nullptr, gin2_b2,
                                               128, 8, g1, nullptr, 0, nullptr, nullptr);
    k_mm<8,0,0,2,0><<<gWide, 256, 0, stream>>>(g1, nullptr, glinf, nullptr, gin_lin_b,
                                               128, 32, Y, fusion_w, 1, nullptr, nullptr);
    // GAT2
    k_mm<8,0,0,0,0><<<gWide, 256, 0, stream>>>(hab, nullptr, ga2f, nullptr, nullptr,
                                               80, 32, h2b, nullptr, 0, nullptr, nullptr);
    k_gat2_al<<<NN, 256, 0, stream>>>(h2b, gat2_as, gat2_ad, als2, ald2);
    k_gat2_attn<<<NN, 256, 0, stream>>>(h2b, als2, ald2, gat2_b, offs, csrc, fusion_w, Y);

    // BN (stats only; apply fused into lin1 staging) + head
    k_bn_stats<<<250, 256, 0, stream>>>(Y, ssum, ssq);
    k_bn_final<<<2, 256, 0, stream>>>(ssum, ssq, mu, inv);
    k_mm<8,0,1,0,1><<<gWide, 256, 0, stream>>>((const u16*)Y, nullptr, l1f, nullptr, lin1_b,
                                               512, 32, y1b, nullptr, 0, mu, inv);
    k_mm<8,0,0,0,0><<<gWide, 256, 0, stream>>>(y1b, nullptr, l2f, nullptr, lin2_b,
                                               512, 32, y2b, nullptr, 0, nullptr, nullptr);

    k_final<<<(NT + 3) / 4, 256, 0, stream>>>(y2b, EI, tid, fc2_W, fc2_b, (float*)d_out);
}